// Round 2
// baseline (114.954 us; speedup 1.0000x reference)
//
#include <hip/hip_runtime.h>

#define QN 32768
#define GN 64
#define BSN 16
#define KM 4
#define GPB 4
#define NTHREADS 512
#define NWAVES (NTHREADS / 64)
#define NLISTS (GPB * 2)

// strict total order on (cost, idx): lower cost first, lower idx on ties
// (matches jax.lax.top_k tie-breaking for smallest-k)
__device__ __forceinline__ bool key_lt(float ca, int ia, float cb, int ib) {
    return (ca < cb) || ((ca == cb) && (ia < ib));
}

struct TopList { float c[KM]; int id[KM]; };

__device__ __forceinline__ void cex(float& c0, int& i0, float& c1, int& i1) {
    bool sw = key_lt(c1, i1, c0, i0);
    float tc0 = sw ? c1 : c0; float tc1 = sw ? c0 : c1;
    int   ti0 = sw ? i1 : i0; int   ti1 = sw ? i0 : i1;
    c0 = tc0; c1 = tc1; i0 = ti0; i1 = ti1;
}

// a (sorted asc) <- lowest-4 of merge(a, b) where b0..b3 sorted asc.
// Bitonic: m_i = lexmin(a_i, b_{3-i}) holds the 4 smallest, then 4-elem
// bitonic clean.
__device__ __forceinline__ void merge4(TopList& a,
    float b0, int j0, float b1, int j1, float b2, int j2, float b3, int j3) {
    float m0, m1, m2, m3; int n0, n1, n2, n3;
    if (key_lt(b3, j3, a.c[0], a.id[0])) { m0 = b3; n0 = j3; } else { m0 = a.c[0]; n0 = a.id[0]; }
    if (key_lt(b2, j2, a.c[1], a.id[1])) { m1 = b2; n1 = j2; } else { m1 = a.c[1]; n1 = a.id[1]; }
    if (key_lt(b1, j1, a.c[2], a.id[2])) { m2 = b1; n2 = j1; } else { m2 = a.c[2]; n2 = a.id[2]; }
    if (key_lt(b0, j0, a.c[3], a.id[3])) { m3 = b0; n3 = j0; } else { m3 = a.c[3]; n3 = a.id[3]; }
    cex(m0, n0, m2, n2); cex(m1, n1, m3, n3);
    cex(m0, n0, m1, n1); cex(m2, n2, m3, n3);
    a.c[0] = m0; a.id[0] = n0; a.c[1] = m1; a.id[1] = n1;
    a.c[2] = m2; a.id[2] = n2; a.c[3] = m3; a.id[3] = n3;
}

// insert candidate into sorted-4 list (rare-taken branch)
__device__ __forceinline__ void upd(TopList& L, float c, int i) {
    if (key_lt(c, i, L.c[3], L.id[3])) {
        L.c[3] = c; L.id[3] = i;
        cex(L.c[2], L.id[2], L.c[3], L.id[3]);
        cex(L.c[1], L.id[1], L.c[2], L.id[2]);
        cex(L.c[0], L.id[0], L.c[1], L.id[1]);
    }
}

__device__ __forceinline__ void eval_q(const TopList* /*dummy*/, TopList* lst,
    const float* gcx, const float* gcy, const float* gww, const float* ghh,
    float4 p, float4 a, int q) {
    float pcx = (p.x + p.z) * 0.5f, pcy = (p.y + p.w) * 0.5f;
    float pw  = p.z - p.x,          ph  = p.w - p.y;
    float acx = (a.x + a.z) * 0.5f, acy = (a.y + a.w) * 0.5f;
    float aw  = a.z - a.x,          ah  = a.w - a.y;
#pragma unroll
    for (int gl = 0; gl < GPB; ++gl) {
        // reference sum order: ((|dcx|+|dcy|)+|dw|)+|dh|
        float cb = ((fabsf(pcx - gcx[gl]) + fabsf(pcy - gcy[gl]))
                    + fabsf(pw - gww[gl])) + fabsf(ph - ghh[gl]);
        upd(lst[gl * 2 + 0], cb, q);
        float ca = ((fabsf(acx - gcx[gl]) + fabsf(acy - gcy[gl]))
                    + fabsf(aw - gww[gl])) + fabsf(ah - ghh[gl]);
        upd(lst[gl * 2 + 1], ca, q);
    }
}

__global__ __launch_bounds__(NTHREADS) void UniformMatcher_kernel(
    const float4* __restrict__ pred, const float4* __restrict__ anc,
    const float4* __restrict__ gt, int* __restrict__ out)
{
    // XCD swizzle: linear block id round-robins over 8 XCDs;
    // give each XCD 2 batches (4 MB working set fits its L2).
    int bid = blockIdx.x;
    int xcd = bid & 7;
    int k   = bid >> 3;                 // 0..31
    int b   = (xcd << 1) | (k & 1);     // 0..15
    int gc  = k >> 1;                   // 0..15

    int tid = threadIdx.x;

    float gcx[GPB], gcy[GPB], gww[GPB], ghh[GPB];
#pragma unroll
    for (int gl = 0; gl < GPB; ++gl) {
        float4 gb = gt[b * GN + gc * GPB + gl];
        gcx[gl] = (gb.x + gb.z) * 0.5f;
        gcy[gl] = (gb.y + gb.w) * 0.5f;
        gww[gl] = gb.z - gb.x;
        ghh[gl] = gb.w - gb.y;
    }

    TopList lst[NLISTS];
#pragma unroll
    for (int l = 0; l < NLISTS; ++l)
#pragma unroll
        for (int s = 0; s < KM; ++s) { lst[l].c[s] = __builtin_inff(); lst[l].id[s] = 0x7fffffff; }

    const float4* pb = pred + (size_t)b * QN;
    const float4* ab = anc  + (size_t)b * QN;

    // 2x unrolled q-loop: issue all 4 loads before consuming (ILP for L2 latency)
    for (int q = tid; q < QN; q += 2 * NTHREADS) {
        float4 p0 = pb[q];
        float4 a0 = ab[q];
        float4 p1 = pb[q + NTHREADS];
        float4 a1 = ab[q + NTHREADS];
        eval_q(nullptr, lst, gcx, gcy, gww, ghh, p0, a0, q);
        eval_q(nullptr, lst, gcx, gcy, gww, ghh, p1, a1, q + NTHREADS);
    }

    // wave-64 butterfly merge: all lanes converge to identical top-4
    for (int off = 1; off < 64; off <<= 1) {
#pragma unroll
        for (int l = 0; l < NLISTS; ++l) {
            float b0 = __shfl_xor(lst[l].c[0], off, 64);
            float b1 = __shfl_xor(lst[l].c[1], off, 64);
            float b2 = __shfl_xor(lst[l].c[2], off, 64);
            float b3 = __shfl_xor(lst[l].c[3], off, 64);
            int   j0 = __shfl_xor(lst[l].id[0], off, 64);
            int   j1 = __shfl_xor(lst[l].id[1], off, 64);
            int   j2 = __shfl_xor(lst[l].id[2], off, 64);
            int   j3 = __shfl_xor(lst[l].id[3], off, 64);
            merge4(lst[l], b0, j0, b1, j1, b2, j2, b3, j3);
        }
    }

    __shared__ float lc[NLISTS][NWAVES][KM];
    __shared__ int   li[NLISTS][NWAVES][KM];
    int lane = tid & 63, wv = tid >> 6;
    if (lane == 0) {
#pragma unroll
        for (int l = 0; l < NLISTS; ++l)
#pragma unroll
            for (int s = 0; s < KM; ++s) { lc[l][wv][s] = lst[l].c[s]; li[l][wv][s] = lst[l].id[s]; }
    }
    __syncthreads();

    if (tid < NLISTS) {
        int l = tid;
        TopList r;
#pragma unroll
        for (int s = 0; s < KM; ++s) { r.c[s] = lc[l][0][s]; r.id[s] = li[l][0][s]; }
        for (int w = 1; w < NWAVES; ++w) {
            merge4(r, lc[l][w][0], li[l][w][0], lc[l][w][1], li[l][w][1],
                      lc[l][w][2], li[l][w][2], lc[l][w][3], li[l][w][3]);
        }
        int gl = l >> 1, type = l & 1;
        int g = gc * GPB + gl;
        int base = b * (2 * KM * GN);
        int* out_j = out + BSN * 2 * KM * GN;
#pragma unroll
        for (int m = 0; m < KM; ++m) {
            // idx_i layout: [b, m, type, g] -> b*512 + m*128 + type*64 + g
            int pos = base + m * (2 * GN) + type * GN + g;
            out[pos]   = r.id[m];
            out_j[pos] = g;
        }
    }
}

extern "C" void kernel_launch(void* const* d_in, const int* in_sizes, int n_in,
                              void* d_out, int out_size, void* d_ws, size_t ws_size,
                              hipStream_t stream) {
    const float4* pred = (const float4*)d_in[0];
    const float4* anc  = (const float4*)d_in[1];
    const float4* gt   = (const float4*)d_in[2];
    int* out = (int*)d_out;
    dim3 grid(BSN * (GN / GPB));   // 256 blocks
    UniformMatcher_kernel<<<grid, NTHREADS, 0, stream>>>(pred, anc, gt, out);
}

// Round 3
// 51.577 us; speedup vs baseline: 2.2288x; 2.2288x over previous
//
#include <hip/hip_runtime.h>

#define QN 32768
#define GN 64
#define BSN 16
#define KM 4
#define GPB 4
#define NTHREADS 1024
#define NWAVES (NTHREADS / 64)
#define NLISTS (GPB * 2)

// Branchless insert of key k into ascending sorted-4 list m (keep 4 smallest).
// 7 x v_min_f64/v_max_f64, no branches, no compares.
__device__ __forceinline__ void ins4(double* m, double k) {
    double t0 = fmin(m[0], k);  double h0 = fmax(m[0], k);
    double t1 = fmin(m[1], h0); double h1 = fmax(m[1], h0);
    double t2 = fmin(m[2], h1); double h2 = fmax(m[2], h1);
    double t3 = fmin(m[3], h2);
    m[0] = t0; m[1] = t1; m[2] = t2; m[3] = t3;
}

// a <- lowest-4 of merge(a, b), both ascending sorted-4. Bitonic, 12 minmax.
__device__ __forceinline__ void merge4s(double* a, const double* b) {
    double m0 = fmin(a[0], b[3]);
    double m1 = fmin(a[1], b[2]);
    double m2 = fmin(a[2], b[1]);
    double m3 = fmin(a[3], b[0]);
    double x0 = fmin(m0, m2), x2 = fmax(m0, m2);
    double x1 = fmin(m1, m3), x3 = fmax(m1, m3);
    a[0] = fmin(x0, x1); a[1] = fmax(x0, x1);
    a[2] = fmin(x2, x3); a[3] = fmax(x2, x3);
}

// key = float_bits(cost) * 2^15 + q  (exact integer < 2^46 in f64).
// cost >= 0 so float bits are order-preserving; lex (cost, q) order; q = key & 32767.
__device__ __forceinline__ double mkkey(float c, double qd) {
    return (double)__float_as_uint(c) * 32768.0 + qd;
}

__device__ __forceinline__ void evalq(double m[NLISTS][KM],
    const float* gcx, const float* gcy, const float* gww, const float* ghh,
    float4 p, float4 a, double qd)
{
    float pcx = (p.x + p.z) * 0.5f, pcy = (p.y + p.w) * 0.5f;
    float pw  = p.z - p.x,          ph  = p.w - p.y;
    float acx = (a.x + a.z) * 0.5f, acy = (a.y + a.w) * 0.5f;
    float aw  = a.z - a.x,          ah  = a.w - a.y;
#pragma unroll
    for (int gl = 0; gl < GPB; ++gl) {
        // reference sum order: ((|dcx|+|dcy|)+|dw|)+|dh|
        float cb = ((fabsf(pcx - gcx[gl]) + fabsf(pcy - gcy[gl]))
                    + fabsf(pw - gww[gl])) + fabsf(ph - ghh[gl]);
        ins4(m[gl * 2 + 0], mkkey(cb, qd));
        float ca = ((fabsf(acx - gcx[gl]) + fabsf(acy - gcy[gl]))
                    + fabsf(aw - gww[gl])) + fabsf(ah - ghh[gl]);
        ins4(m[gl * 2 + 1], mkkey(ca, qd));
    }
}

__global__ __launch_bounds__(NTHREADS, 4) void UniformMatcher_kernel(
    const float4* __restrict__ pred, const float4* __restrict__ anc,
    const float4* __restrict__ gt, int* __restrict__ out)
{
    // XCD swizzle: linear block id round-robins over 8 XCDs;
    // 2 batches per XCD so the 4 MB working set fits its private L2.
    int bid = blockIdx.x;
    int xcd = bid & 7;
    int k   = bid >> 3;                 // 0..31
    int b   = (xcd << 1) | (k & 1);     // 0..15
    int gc  = k >> 1;                   // 0..15

    int tid = threadIdx.x;

    float gcx[GPB], gcy[GPB], gww[GPB], ghh[GPB];
#pragma unroll
    for (int gl = 0; gl < GPB; ++gl) {
        float4 gb = gt[b * GN + gc * GPB + gl];
        gcx[gl] = (gb.x + gb.z) * 0.5f;
        gcy[gl] = (gb.y + gb.w) * 0.5f;
        gww[gl] = gb.z - gb.x;
        ghh[gl] = gb.w - gb.y;
    }

    double m[NLISTS][KM];
#pragma unroll
    for (int l = 0; l < NLISTS; ++l)
#pragma unroll
        for (int s = 0; s < KM; ++s) m[l][s] = __builtin_inf();

    const float4* pb = pred + (size_t)b * QN;
    const float4* ab = anc  + (size_t)b * QN;

    // 32 q per thread; 2x unrolled for load ILP
    for (int q = tid; q < QN; q += 2 * NTHREADS) {
        float4 p0 = pb[q];
        float4 a0 = ab[q];
        float4 p1 = pb[q + NTHREADS];
        float4 a1 = ab[q + NTHREADS];
        evalq(m, gcx, gcy, gww, ghh, p0, a0, (double)q);
        evalq(m, gcx, gcy, gww, ghh, p1, a1, (double)(q + NTHREADS));
    }

    // wave-64 butterfly: all lanes converge to identical sorted top-4
    for (int off = 1; off < 64; off <<= 1) {
#pragma unroll
        for (int l = 0; l < NLISTS; ++l) {
            double bb[KM];
#pragma unroll
            for (int s = 0; s < KM; ++s) bb[s] = __shfl_xor(m[l][s], off, 64);
            merge4s(m[l], bb);
        }
    }

    __shared__ double smem[NLISTS][NWAVES][KM];   // 4 KB
    int lane = tid & 63, wv = tid >> 6;
    if (lane == 0) {
#pragma unroll
        for (int l = 0; l < NLISTS; ++l)
#pragma unroll
            for (int s = 0; s < KM; ++s) smem[l][wv][s] = m[l][s];
    }
    __syncthreads();

    if (tid < NLISTS) {
        int l = tid;
        double r[KM];
#pragma unroll
        for (int s = 0; s < KM; ++s) r[s] = smem[l][0][s];
        for (int w = 1; w < NWAVES; ++w) {
            double bb[KM];
#pragma unroll
            for (int s = 0; s < KM; ++s) bb[s] = smem[l][w][s];
            merge4s(r, bb);
        }
        int gl = l >> 1, type = l & 1;
        int g = gc * GPB + gl;
        int base = b * (2 * KM * GN);
        int* out_j = out + BSN * 2 * KM * GN;
#pragma unroll
        for (int mm = 0; mm < KM; ++mm) {
            int qi = (int)((unsigned long long)r[mm] & 32767ull);
            // idx_i layout: [b, m, type, g] -> b*512 + m*128 + type*64 + g
            int pos = base + mm * (2 * GN) + type * GN + g;
            out[pos]   = qi;
            out_j[pos] = g;
        }
    }
}

extern "C" void kernel_launch(void* const* d_in, const int* in_sizes, int n_in,
                              void* d_out, int out_size, void* d_ws, size_t ws_size,
                              hipStream_t stream) {
    const float4* pred = (const float4*)d_in[0];
    const float4* anc  = (const float4*)d_in[1];
    const float4* gt   = (const float4*)d_in[2];
    int* out = (int*)d_out;
    dim3 grid(BSN * (GN / GPB));   // 256 blocks
    UniformMatcher_kernel<<<grid, NTHREADS, 0, stream>>>(pred, anc, gt, out);
}